// Round 1
// baseline (82.303 us; speedup 1.0000x reference)
//
#include <hip/hip_runtime.h>

#define GAMMA   0.99f
#define EPSILON 1e-8f
#define CLIPR   10.0f
#define VAR_MOM 0.99f

constexpr int T = 4096;
constexpr int B = 4096;

// Kernel 1: per (chunk c, column b) compute carry-independent chunk summaries.
// ret[t] = v_t + p_t * carry_in  for t in [c*L, (c+1)*L)
__global__ void chunk_scan(const float* __restrict__ rewards,
                           const float* __restrict__ dones,
                           float* __restrict__ arrs,   // 7 arrays, stride S=C*B
                           int C, int L) {
    const int b = blockIdx.x * blockDim.x + threadIdx.x;
    const int c = blockIdx.y;
    const int t0 = c * L;

    float v = 0.f, p = 1.f;
    float sv = 0.f, sp = 0.f, sv2 = 0.f, svp = 0.f, sp2 = 0.f;

    for (int t = t0 + L - 1; t >= t0; --t) {
        const size_t off = (size_t)t * B + b;
        const float r = rewards[off];
        const float d = dones[off];
        const float a = GAMMA - GAMMA * d;   // gamma * (1 - d)
        v = fmaf(a, v, r);                   // local scan (carry = 0)
        p = p * a;                           // suffix decay product
        sv  += v;
        sp  += p;
        sv2  = fmaf(v, v, sv2);
        svp  = fmaf(v, p, svp);
        sp2  = fmaf(p, p, sp2);
    }

    const size_t S   = (size_t)C * B;
    const size_t idx = (size_t)c * B + b;
    arrs[0 * S + idx] = v;    // v_first (value at chunk start, zero carry)
    arrs[1 * S + idx] = p;    // p_tot   (full-chunk decay product)
    arrs[2 * S + idx] = sv;
    arrs[3 * S + idx] = sp;
    arrs[4 * S + idx] = sv2;
    arrs[5 * S + idx] = svp;
    arrs[6 * S + idx] = sp2;
}

// Kernel 2: per column, propagate carry across chunks (reverse time order),
// accumulate exact column sum / sumsq in double, reduce, atomic to acc[0..1].
__global__ void carry_reduce(const float* __restrict__ arrs, int C,
                             const float* __restrict__ return_init,
                             double* __restrict__ acc) {
    const int b = blockIdx.x * blockDim.x + threadIdx.x;
    const size_t S = (size_t)C * B;

    double s = 0.0, s2 = 0.0;
    float carry = return_init[0];
    for (int c = C - 1; c >= 0; --c) {
        const size_t idx = (size_t)c * B + b;
        const float vf  = arrs[0 * S + idx];
        const float pt  = arrs[1 * S + idx];
        const float sv  = arrs[2 * S + idx];
        const float sp  = arrs[3 * S + idx];
        const float sv2 = arrs[4 * S + idx];
        const float svp = arrs[5 * S + idx];
        const float sp2 = arrs[6 * S + idx];
        const double cd = (double)carry;
        s  += (double)sv  + cd * (double)sp;
        s2 += (double)sv2 + 2.0 * cd * (double)svp + cd * cd * (double)sp2;
        carry = fmaf(pt, carry, vf);
    }

    __shared__ double sh_s[256];
    __shared__ double sh_s2[256];
    const int tid = threadIdx.x;
    sh_s[tid] = s;
    sh_s2[tid] = s2;
    __syncthreads();
    for (int stride = 128; stride > 0; stride >>= 1) {
        if (tid < stride) {
            sh_s[tid]  += sh_s[tid + stride];
            sh_s2[tid] += sh_s2[tid + stride];
        }
        __syncthreads();
    }
    if (tid == 0) {
        atomicAdd(&acc[0], sh_s[0]);
        atomicAdd(&acc[1], sh_s2[0]);
    }
}

// Kernel 3: scale = 1/sqrt(var_new + eps); out = clip(rewards * scale).
__global__ void normalize(const float* __restrict__ rewards,
                          float* __restrict__ out,
                          const double* __restrict__ acc,
                          const float* __restrict__ var_init,
                          int n4) {
    const double s  = acc[0];
    const double s2 = acc[1];
    const double n  = (double)T * (double)B;
    const double ret_var = (s2 - s * s / n) / (n - 1.0);   // ddof=1
    const float var_new = (float)((double)var_init[0] * (double)VAR_MOM +
                                  ret_var * (1.0 - (double)VAR_MOM));
    const float scale = 1.0f / sqrtf(var_new + EPSILON);

    const float4* __restrict__ r4 = (const float4*)rewards;
    float4* __restrict__ o4 = (float4*)out;
    const int stride = gridDim.x * blockDim.x;
    for (int i = blockIdx.x * blockDim.x + threadIdx.x; i < n4; i += stride) {
        float4 x = r4[i];
        float4 y;
        y.x = fminf(fmaxf(x.x * scale, -CLIPR), CLIPR);
        y.y = fminf(fmaxf(x.y * scale, -CLIPR), CLIPR);
        y.z = fminf(fmaxf(x.z * scale, -CLIPR), CLIPR);
        y.w = fminf(fmaxf(x.w * scale, -CLIPR), CLIPR);
        o4[i] = y;
    }
}

extern "C" void kernel_launch(void* const* d_in, const int* in_sizes, int n_in,
                              void* d_out, int out_size, void* d_ws, size_t ws_size,
                              hipStream_t stream) {
    const float* rewards     = (const float*)d_in[0];
    const float* dones       = (const float*)d_in[1];
    const float* return_init = (const float*)d_in[2];
    const float* var_init    = (const float*)d_in[3];
    float* out = (float*)d_out;

    // Choose chunk count C (power of two dividing T) to fit workspace:
    // layout: [0,16) two f64 accumulators; [64, 64 + 7*C*B*4) chunk arrays.
    int C = 64;
    while (C > 1 && (size_t)(64 + (size_t)7 * C * B * 4) > ws_size) C >>= 1;
    const int L = T / C;

    double* acc  = (double*)d_ws;
    float*  arrs = (float*)((char*)d_ws + 64);

    hipMemsetAsync(d_ws, 0, 16, stream);   // zero the two f64 accumulators

    dim3 g1(B / 256, C);
    chunk_scan<<<g1, 256, 0, stream>>>(rewards, dones, arrs, C, L);

    carry_reduce<<<B / 256, 256, 0, stream>>>(arrs, C, return_init, acc);

    const int n4 = (T * B) / 4;
    normalize<<<2048, 256, 0, stream>>>(rewards, out, acc, var_init, n4);
}

// Round 2
// 73.224 us; speedup vs baseline: 1.1240x; 1.1240x over previous
//
#include <hip/hip_runtime.h>

#define GAMMA   0.99f
#define EPSILON 1e-8f
#define CLIPR   10.0f
#define VAR_MOM 0.99f

constexpr int T = 4096;
constexpr int B = 4096;

// Kernel 1: per (chunk c, column-group g) compute carry-independent chunk
// summaries for VPT adjacent columns. ret[t] = v_t + p_t * carry_in.
template <int L, int VPT>
__global__ void chunk_scan_k(const float* __restrict__ rewards,
                             const float* __restrict__ dones,
                             float* __restrict__ arrs,   // 7 arrays, stride S=C*B
                             int C) {
    const int g    = blockIdx.x * blockDim.x + threadIdx.x;  // [0, B/VPT)
    const int c    = blockIdx.y;
    const int col0 = g * VPT;
    const int t0   = c * L;

    float v[VPT], p[VPT], sv[VPT], sp[VPT], sv2[VPT], svp[VPT], sp2[VPT];
#pragma unroll
    for (int k = 0; k < VPT; ++k) {
        v[k] = 0.f; p[k] = 1.f;
        sv[k] = 0.f; sp[k] = 0.f; sv2[k] = 0.f; svp[k] = 0.f; sp2[k] = 0.f;
    }

#pragma unroll 4
    for (int t = t0 + L - 1; t >= t0; --t) {
        const float* rp = rewards + (size_t)t * B + col0;
        const float* dp = dones   + (size_t)t * B + col0;
        float r[VPT], d[VPT];
        if constexpr (VPT == 4) {
            const float4 rv = *(const float4*)rp;
            const float4 dv = *(const float4*)dp;
            r[0] = rv.x; r[1] = rv.y; r[2] = rv.z; r[3] = rv.w;
            d[0] = dv.x; d[1] = dv.y; d[2] = dv.z; d[3] = dv.w;
        } else if constexpr (VPT == 2) {
            const float2 rv = *(const float2*)rp;
            const float2 dv = *(const float2*)dp;
            r[0] = rv.x; r[1] = rv.y;
            d[0] = dv.x; d[1] = dv.y;
        } else {
            r[0] = rp[0];
            d[0] = dp[0];
        }
#pragma unroll
        for (int k = 0; k < VPT; ++k) {
            const float a = GAMMA - GAMMA * d[k];   // gamma * (1 - d)
            v[k] = fmaf(a, v[k], r[k]);             // local scan (carry = 0)
            p[k] = p[k] * a;                        // suffix decay product
            sv[k]  += v[k];
            sp[k]  += p[k];
            sv2[k]  = fmaf(v[k], v[k], sv2[k]);
            svp[k]  = fmaf(v[k], p[k], svp[k]);
            sp2[k]  = fmaf(p[k], p[k], sp2[k]);
        }
    }

    const size_t S   = (size_t)C * B;
    const size_t idx = (size_t)c * B + col0;
    float* a0 = arrs;
    // coalesced vector stores per array
    const float* srcs[7] = {v, p, sv, sp, sv2, svp, sp2};
#pragma unroll
    for (int a = 0; a < 7; ++a) {
        float* dst = a0 + (size_t)a * S + idx;
        if constexpr (VPT == 4) {
            float4 w; w.x = srcs[a][0]; w.y = srcs[a][1]; w.z = srcs[a][2]; w.w = srcs[a][3];
            *(float4*)dst = w;
        } else if constexpr (VPT == 2) {
            float2 w; w.x = srcs[a][0]; w.y = srcs[a][1];
            *(float2*)dst = w;
        } else {
            dst[0] = srcs[a][0];
        }
    }
}

// Kernel 2: per column, propagate carry across chunks (reverse time order),
// accumulate exact column sum / sumsq in double, reduce, atomic to acc[0..1].
__global__ void carry_reduce(const float* __restrict__ arrs, int C,
                             const float* __restrict__ return_init,
                             double* __restrict__ acc) {
    const int b = blockIdx.x * blockDim.x + threadIdx.x;
    const size_t S = (size_t)C * B;

    double s = 0.0, s2 = 0.0;
    float carry = return_init[0];
#pragma unroll 4
    for (int c = C - 1; c >= 0; --c) {
        const size_t idx = (size_t)c * B + b;
        const float vf  = arrs[0 * S + idx];
        const float pt  = arrs[1 * S + idx];
        const float sv  = arrs[2 * S + idx];
        const float sp  = arrs[3 * S + idx];
        const float sv2 = arrs[4 * S + idx];
        const float svp = arrs[5 * S + idx];
        const float sp2 = arrs[6 * S + idx];
        const double cd = (double)carry;
        s  += (double)sv  + cd * (double)sp;
        s2 += (double)sv2 + 2.0 * cd * (double)svp + cd * cd * (double)sp2;
        carry = fmaf(pt, carry, vf);
    }

    __shared__ double sh_s[256];
    __shared__ double sh_s2[256];
    const int tid = threadIdx.x;
    sh_s[tid] = s;
    sh_s2[tid] = s2;
    __syncthreads();
    for (int stride = 128; stride > 0; stride >>= 1) {
        if (tid < stride) {
            sh_s[tid]  += sh_s[tid + stride];
            sh_s2[tid] += sh_s2[tid + stride];
        }
        __syncthreads();
    }
    if (tid == 0) {
        atomicAdd(&acc[0], sh_s[0]);
        atomicAdd(&acc[1], sh_s2[0]);
    }
}

// Kernel 3: scale = 1/sqrt(var_new + eps); out = clip(rewards * scale).
__global__ void normalize(const float* __restrict__ rewards,
                          float* __restrict__ out,
                          const double* __restrict__ acc,
                          const float* __restrict__ var_init,
                          int n4) {
    const double s  = acc[0];
    const double s2 = acc[1];
    const double n  = (double)T * (double)B;
    const double ret_var = (s2 - s * s / n) / (n - 1.0);   // ddof=1
    const float var_new = (float)((double)var_init[0] * (double)VAR_MOM +
                                  ret_var * (1.0 - (double)VAR_MOM));
    const float scale = 1.0f / sqrtf(var_new + EPSILON);

    const float4* __restrict__ r4 = (const float4*)rewards;
    float4* __restrict__ o4 = (float4*)out;
    const int stride = gridDim.x * blockDim.x;
    for (int i = blockIdx.x * blockDim.x + threadIdx.x; i < n4; i += stride) {
        float4 x = r4[i];
        float4 y;
        y.x = fminf(fmaxf(x.x * scale, -CLIPR), CLIPR);
        y.y = fminf(fmaxf(x.y * scale, -CLIPR), CLIPR);
        y.z = fminf(fmaxf(x.z * scale, -CLIPR), CLIPR);
        y.w = fminf(fmaxf(x.w * scale, -CLIPR), CLIPR);
        o4[i] = y;
    }
}

extern "C" void kernel_launch(void* const* d_in, const int* in_sizes, int n_in,
                              void* d_out, int out_size, void* d_ws, size_t ws_size,
                              hipStream_t stream) {
    const float* rewards     = (const float*)d_in[0];
    const float* dones       = (const float*)d_in[1];
    const float* return_init = (const float*)d_in[2];
    const float* var_init    = (const float*)d_in[3];
    float* out = (float*)d_out;

    double* acc  = (double*)d_ws;
    float*  arrs = (float*)((char*)d_ws + 64);

    hipMemsetAsync(d_ws, 0, 16, stream);   // zero the two f64 accumulators

    // Pick largest chunk count C whose 7*C*B*4 scratch fits ws_size.
    const size_t need128 = 64 + (size_t)7 * 128 * B * 4;
    const size_t need64  = 64 + (size_t)7 * 64  * B * 4;
    int C;
    if (ws_size >= need128) {
        C = 128;   // L=32, VPT=4 -> 2048 waves, 16B/lane loads
        dim3 g1(B / 4 / 256, C);
        chunk_scan_k<32, 4><<<g1, 256, 0, stream>>>(rewards, dones, arrs, C);
    } else if (ws_size >= need64) {
        C = 64;    // L=64, VPT=2 -> 2048 waves, 8B/lane loads
        dim3 g1(B / 2 / 256, C);
        chunk_scan_k<64, 2><<<g1, 256, 0, stream>>>(rewards, dones, arrs, C);
    } else {
        C = 32;    // L=128, VPT=1 -> 2048 waves, 4B/lane loads
        dim3 g1(B / 256, C);
        chunk_scan_k<128, 1><<<g1, 256, 0, stream>>>(rewards, dones, arrs, C);
    }

    carry_reduce<<<B / 256, 256, 0, stream>>>(arrs, C, return_init, acc);

    const int n4 = (T * B) / 4;
    normalize<<<4096, 256, 0, stream>>>(rewards, out, acc, var_init, n4);
}

// Round 3
// 65.980 us; speedup vs baseline: 1.2474x; 1.1098x over previous
//
#include <hip/hip_runtime.h>

#define GAMMA   0.99f
#define EPSILON 1e-8f
#define CLIPR   10.0f
#define VAR_MOM 0.99f

constexpr int T = 4096;
constexpr int B = 4096;
constexpr int GSEG = 16;   // segments per column for two-level carry pass

// ---------------------------------------------------------------------------
// K1: per (chunk c, column pair g) compute carry-independent chunk summaries.
// ret[t] = v_t + p_t * carry_in. Explicit D-deep software pipeline: buffers
// rotate with compile-time indices (full unroll), ~2*D load instrs in flight.
// ---------------------------------------------------------------------------
template <int L, int D>
__global__ __launch_bounds__(256) void chunk_scan_k(
    const float2* __restrict__ rewards,
    const float2* __restrict__ dones,
    float* __restrict__ arrs,   // 7 arrays, stride S=C*B
    int C) {
    const int g = blockIdx.x * blockDim.x + threadIdx.x;  // [0, B/2)
    const int c = blockIdx.y;
    const int W = B / 2;
    const size_t base = (size_t)c * L * W + g;

    float2 rbuf[D], dbuf[D];
#pragma unroll
    for (int j = 0; j < D; ++j) {
        const size_t off = base + (size_t)(L - 1 - j) * W;
        rbuf[j] = rewards[off];
        dbuf[j] = dones[off];
    }

    float v0 = 0.f, p0 = 1.f, sv0 = 0.f, sp0 = 0.f, sv20 = 0.f, svp0 = 0.f, sp20 = 0.f;
    float v1 = 0.f, p1 = 1.f, sv1 = 0.f, sp1 = 0.f, sv21 = 0.f, svp1 = 0.f, sp21 = 0.f;

#pragma unroll
    for (int j = 0; j < L; ++j) {
        const float2 rv = rbuf[j & (D - 1)];
        const float2 dv = dbuf[j & (D - 1)];
        if (j + D < L) {   // compile-time after unroll
            const size_t off = base + (size_t)(L - 1 - j - D) * W;
            rbuf[j & (D - 1)] = rewards[off];
            dbuf[j & (D - 1)] = dones[off];
        }
        const float a0 = GAMMA - GAMMA * dv.x;
        const float a1 = GAMMA - GAMMA * dv.y;
        v0 = fmaf(a0, v0, rv.x);  p0 *= a0;
        v1 = fmaf(a1, v1, rv.y);  p1 *= a1;
        sv0 += v0;  sp0 += p0;
        sv20 = fmaf(v0, v0, sv20);  svp0 = fmaf(v0, p0, svp0);  sp20 = fmaf(p0, p0, sp20);
        sv1 += v1;  sp1 += p1;
        sv21 = fmaf(v1, v1, sv21);  svp1 = fmaf(v1, p1, svp1);  sp21 = fmaf(p1, p1, sp21);
    }

    const size_t S   = (size_t)C * B;
    const size_t idx = (size_t)c * B + 2 * g;
    *(float2*)&arrs[0 * S + idx] = make_float2(v0,  v1);    // v_first
    *(float2*)&arrs[1 * S + idx] = make_float2(p0,  p1);    // p_tot
    *(float2*)&arrs[2 * S + idx] = make_float2(sv0, sv1);
    *(float2*)&arrs[3 * S + idx] = make_float2(sp0, sp1);
    *(float2*)&arrs[4 * S + idx] = make_float2(sv20, sv21);
    *(float2*)&arrs[5 * S + idx] = make_float2(svp0, svp1);
    *(float2*)&arrs[6 * S + idx] = make_float2(sp20, sp21);
}

// ---------------------------------------------------------------------------
// K2a: compose chunk summaries within each of GSEG segments per column.
// The 7-tuple is closed under composition (affine carry, quadratic sums).
// ---------------------------------------------------------------------------
__global__ void seg_compose(const float* __restrict__ arrs, int C,
                            float* __restrict__ seg) {
    const int tid = blockIdx.x * blockDim.x + threadIdx.x;
    const int b = tid & (B - 1);
    const int s = tid >> 12;           // / B
    const int Cs = C / GSEG;
    const size_t S = (size_t)C * B;

    float V = 0.f, P = 1.f, SV = 0.f, SP = 0.f, SV2 = 0.f, SVP = 0.f, SP2 = 0.f;
    for (int c = (s + 1) * Cs - 1; c >= s * Cs; --c) {
        const size_t idx = (size_t)c * B + b;
        const float vf  = arrs[0 * S + idx];
        const float pt  = arrs[1 * S + idx];
        const float sv  = arrs[2 * S + idx];
        const float sp  = arrs[3 * S + idx];
        const float sv2 = arrs[4 * S + idx];
        const float svp = arrs[5 * S + idx];
        const float sp2 = arrs[6 * S + idx];
        // incoming carry for chunk c is (V + P*x); x = segment-incoming carry
        SV2 += sv2 + 2.f * svp * V + sp2 * V * V;
        SVP += svp * P + sp2 * V * P;
        SP2 += sp2 * P * P;
        SV  += sv + sp * V;
        SP  += sp * P;
        V = fmaf(pt, V, vf);
        P *= pt;
    }
    const size_t SG = (size_t)GSEG * B;
    const size_t o  = (size_t)s * B + b;
    seg[0 * SG + o] = V;   seg[1 * SG + o] = P;
    seg[2 * SG + o] = SV;  seg[3 * SG + o] = SP;
    seg[4 * SG + o] = SV2; seg[5 * SG + o] = SVP; seg[6 * SG + o] = SP2;
}

// K2b: finish carry across GSEG segments per column; exact sums in double.
__global__ void carry_final(const float* __restrict__ seg,
                            const float* __restrict__ return_init,
                            double* __restrict__ acc) {
    const int b = blockIdx.x * blockDim.x + threadIdx.x;
    const size_t SG = (size_t)GSEG * B;
    double s = 0.0, s2 = 0.0;
    float carry = return_init[0];
    for (int g = GSEG - 1; g >= 0; --g) {
        const size_t o = (size_t)g * B + b;
        const float V   = seg[0 * SG + o];
        const float P   = seg[1 * SG + o];
        const float SV  = seg[2 * SG + o];
        const float SP  = seg[3 * SG + o];
        const float SV2 = seg[4 * SG + o];
        const float SVP = seg[5 * SG + o];
        const float SP2 = seg[6 * SG + o];
        const double cd = (double)carry;
        s  += (double)SV  + cd * (double)SP;
        s2 += (double)SV2 + 2.0 * cd * (double)SVP + cd * cd * (double)SP2;
        carry = fmaf(P, carry, V);
    }
    __shared__ double sh_s[256];
    __shared__ double sh_s2[256];
    const int tid = threadIdx.x;
    sh_s[tid] = s; sh_s2[tid] = s2;
    __syncthreads();
    for (int stride = 128; stride > 0; stride >>= 1) {
        if (tid < stride) {
            sh_s[tid]  += sh_s[tid + stride];
            sh_s2[tid] += sh_s2[tid + stride];
        }
        __syncthreads();
    }
    if (tid == 0) {
        atomicAdd(&acc[0], sh_s[0]);
        atomicAdd(&acc[1], sh_s2[0]);
    }
}

// K2 fallback (single-level) if ws too small for seg scratch.
__global__ void carry_reduce(const float* __restrict__ arrs, int C,
                             const float* __restrict__ return_init,
                             double* __restrict__ acc) {
    const int b = blockIdx.x * blockDim.x + threadIdx.x;
    const size_t S = (size_t)C * B;
    double s = 0.0, s2 = 0.0;
    float carry = return_init[0];
#pragma unroll 4
    for (int c = C - 1; c >= 0; --c) {
        const size_t idx = (size_t)c * B + b;
        const float vf  = arrs[0 * S + idx];
        const float pt  = arrs[1 * S + idx];
        const float sv  = arrs[2 * S + idx];
        const float sp  = arrs[3 * S + idx];
        const float sv2 = arrs[4 * S + idx];
        const float svp = arrs[5 * S + idx];
        const float sp2 = arrs[6 * S + idx];
        const double cd = (double)carry;
        s  += (double)sv  + cd * (double)sp;
        s2 += (double)sv2 + 2.0 * cd * (double)svp + cd * cd * (double)sp2;
        carry = fmaf(pt, carry, vf);
    }
    __shared__ double sh_s[256];
    __shared__ double sh_s2[256];
    const int tid = threadIdx.x;
    sh_s[tid] = s; sh_s2[tid] = s2;
    __syncthreads();
    for (int stride = 128; stride > 0; stride >>= 1) {
        if (tid < stride) {
            sh_s[tid]  += sh_s[tid + stride];
            sh_s2[tid] += sh_s2[tid + stride];
        }
        __syncthreads();
    }
    if (tid == 0) {
        atomicAdd(&acc[0], sh_s[0]);
        atomicAdd(&acc[1], sh_s2[0]);
    }
}

// K3: scale = 1/sqrt(var_new + eps); out = clip(rewards * scale).
__global__ void normalize(const float* __restrict__ rewards,
                          float* __restrict__ out,
                          const double* __restrict__ acc,
                          const float* __restrict__ var_init,
                          int n4) {
    const double s  = acc[0];
    const double s2 = acc[1];
    const double n  = (double)T * (double)B;
    const double ret_var = (s2 - s * s / n) / (n - 1.0);   // ddof=1
    const float var_new = (float)((double)var_init[0] * (double)VAR_MOM +
                                  ret_var * (1.0 - (double)VAR_MOM));
    const float scale = 1.0f / sqrtf(var_new + EPSILON);

    const float4* __restrict__ r4 = (const float4*)rewards;
    float4* __restrict__ o4 = (float4*)out;
    const int stride = gridDim.x * blockDim.x;
    for (int i = blockIdx.x * blockDim.x + threadIdx.x; i < n4; i += stride) {
        float4 x = r4[i];
        float4 y;
        y.x = fminf(fmaxf(x.x * scale, -CLIPR), CLIPR);
        y.y = fminf(fmaxf(x.y * scale, -CLIPR), CLIPR);
        y.z = fminf(fmaxf(x.z * scale, -CLIPR), CLIPR);
        y.w = fminf(fmaxf(x.w * scale, -CLIPR), CLIPR);
        o4[i] = y;
    }
}

extern "C" void kernel_launch(void* const* d_in, const int* in_sizes, int n_in,
                              void* d_out, int out_size, void* d_ws, size_t ws_size,
                              hipStream_t stream) {
    const float* rewards     = (const float*)d_in[0];
    const float* dones       = (const float*)d_in[1];
    const float* return_init = (const float*)d_in[2];
    const float* var_init    = (const float*)d_in[3];
    float* out = (float*)d_out;

    double* acc  = (double*)d_ws;
    float*  arrs = (float*)((char*)d_ws + 64);

    hipMemsetAsync(d_ws, 0, 16, stream);   // zero the two f64 accumulators

    const size_t arrs128 = (size_t)7 * 128 * B * 4;
    const size_t arrs64  = (size_t)7 * 64  * B * 4;
    const size_t segsz   = (size_t)7 * GSEG * B * 4;

    const float2* r2 = (const float2*)rewards;
    const float2* d2 = (const float2*)dones;

    int C;
    float* segp = nullptr;
    if (ws_size >= 64 + arrs128 + segsz) {
        C = 128;  segp = (float*)((char*)d_ws + 64 + arrs128);
        dim3 g1((B / 2) / 256, C);
        chunk_scan_k<32, 8><<<g1, 256, 0, stream>>>(r2, d2, arrs, C);
    } else if (ws_size >= 64 + arrs128) {
        C = 128;
        dim3 g1((B / 2) / 256, C);
        chunk_scan_k<32, 8><<<g1, 256, 0, stream>>>(r2, d2, arrs, C);
    } else {
        C = 64;
        if (ws_size >= 64 + arrs64 + segsz) segp = (float*)((char*)d_ws + 64 + arrs64);
        dim3 g1((B / 2) / 256, C);
        chunk_scan_k<64, 8><<<g1, 256, 0, stream>>>(r2, d2, arrs, C);
    }

    if (segp) {
        seg_compose<<<(B * GSEG) / 256, 256, 0, stream>>>(arrs, C, segp);
        carry_final<<<B / 256, 256, 0, stream>>>(segp, return_init, acc);
    } else {
        carry_reduce<<<B / 256, 256, 0, stream>>>(arrs, C, return_init, acc);
    }

    const int n4 = (T * B) / 4;
    normalize<<<4096, 256, 0, stream>>>(rewards, out, acc, var_init, n4);
}